// Round 13
// baseline (122.713 us; speedup 1.0000x reference)
//
#include <hip/hip_runtime.h>

// SimplePitchEstimator on MI355X (gfx950).
// Round-13: DIAGNOSTIC x2-rep of the EXACT round-12 kernel (best, absmax 0).
//
// Why: pitch_kernel has been below the harness's ~42 us fillBuffer wall for
// 5 rounds (no counters), and rocprof-inflated dispatch times made overhead
// estimates unreliable. Running the identical body twice in one dispatch:
//   (1) dur_us(r13) - dur_us(r12) = TRUE single-pass kernel time, clean of
//       all harness/profiling ambiguity;
//   (2) the ~2x dispatch surfaces into top-5 with full counters ->
//       VALUBusy >=75% = issue-bound (next: instruction diet);
//       VALUBusy <=55% = latency/barrier-bound (next: staging pipeline);
//       WRITE_SIZE >> 1 MB = rotation conv secretly spills (revert).
//
// Body is byte-identical r12 except: rep loop (opaque-zero asm offset defeats
// load CSE/LICM so phase A re-executes; barrier before phase B protects the
// aux rows from the previous rep's phase-F reads). Output write idempotent.

#define SR_F    16000.0f
#define HOPSZ   256
#define TFRAMES 4096
#define SAMPLES 1048576

#define CMP(v_, c_) ((c_) == 0 ? (v_).x : (c_) == 1 ? (v_).y : \
                     (c_) == 2 ? (v_).z : (v_).w)

template<int N0>
__device__ __forceinline__ void conv_tile(const float4* __restrict__ col4,
                                          const float* __restrict__ colf,
                                          float& best, int& bl) {
    constexpr int J    = 15;
    constexpr int B0   = ((N0 - 3) / 4) * 4;   // aligned window base row
    constexpr int Q0   = B0 / 4;               // base quad at round 0
    constexpr int KOFF = N0 - B0;              // 3..6
    constexpr int IC   = (N0 + J) / 2;         // i-count for max lag
    constexpr int RT   = (IC + 3) / 4;         // total rounds
    constexpr int RC   = (N0 - 6 + 7) / 8;     // clean rounds (8r+6 < N0)
    constexpr int T    = RC / 6;               // runtime x6 trips
    constexpr int R6   = 6 * T;                // first static round
    static_assert(KOFF >= 3 && KOFF + J - 1 <= 20, "window index bound");
    static_assert(RC >= 1 && RC <= RT - 1, "clean/ragged split");
    static_assert(Q0 - RT + 1 >= 0, "refill quad in range");

    float acc[J];
    #pragma unroll
    for (int j = 0; j < J; ++j) acc[j] = 0.f;

    float4 W0_, W1_, W2_, W3_, W4_, W5_, xa_, xb_;

#define WREAD(vi_, c_) \
    ((vi_) == 0 ? CMP(W0_, c_) : (vi_) == 1 ? CMP(W1_, c_) : \
     (vi_) == 2 ? CMP(W2_, c_) : (vi_) == 3 ? CMP(W3_, c_) : \
     (vi_) == 4 ? CMP(W4_, c_) : CMP(W5_, c_))

#define WSTORE(vi_, e_) do {                                              \
    if      ((vi_) == 0) W0_ = (e_); else if ((vi_) == 1) W1_ = (e_);     \
    else if ((vi_) == 2) W2_ = (e_); else if ((vi_) == 3) W3_ = (e_);     \
    else if ((vi_) == 4) W4_ = (e_); else                 W5_ = (e_);     \
    } while (0)

#define ROUND_BODY(K_, R_, MASKED_)                                       \
    {                                                                     \
        const float4 xc = ((R_) & 1) ? xb_ : xa_;                         \
        _Pragma("unroll")                                                 \
        for (int d = 0; d < 4; ++d) {                                     \
            const float xv = CMP(xc, d);                                  \
            _Pragma("unroll")                                             \
            for (int j = 0; j < J; ++j) {                                 \
                if (!(MASKED_) || (8 * (R_) + 2 * d < N0 + j)) {          \
                    const int g  = KOFF + j - d;                          \
                    const int vi = ((Q0 + g / 4 - (K_)) % 6 + 6) % 6;     \
                    acc[j] = fmaf(xv, WREAD(vi, g & 3), acc[j]);          \
                }                                                         \
            }                                                             \
        }                                                                 \
    }

    // ---- init: quads Q0..Q0+5 into vars (Q0+i)%6 (clip quads>39), x quad 0
    #pragma unroll
    for (int i = 0; i < 6; ++i) {
        const float4 q = (Q0 + i <= 39) ? col4[(Q0 + i) * 64]
                                        : make_float4(0.f, 0.f, 0.f, 0.f);
        WSTORE((Q0 + i) % 6, q);
    }
    xa_ = col4[0];

    // ---- runtime x6 trips: rounds r = 6t+k, all clean ----
    const float4* xq = col4;                 // x base: quad 6t
    const float4* wq = col4 + Q0 * 64;       // refill base: quad Q0-6t
    #pragma unroll 1
    for (int t = 0; t < T; ++t) {
        #pragma unroll
        for (int k = 0; k < 6; ++k) {
            if (((k + 1) & 1) == 0) xa_ = xq[(k + 1) * 64];
            else                    xb_ = xq[(k + 1) * 64];
            ROUND_BODY(k, k, 0)
            WSTORE(((Q0 - k - 1) % 6 + 6) % 6, wq[-(k + 1) * 64]);
        }
        xq += 6 * 64;
        wq -= 6 * 64;
    }

    // ---- static rounds rr = R6..RT-1 (clean remainder + ragged) ----
    #pragma unroll
    for (int u = 0; u < RT - R6; ++u) {
        const int rr = R6 + u;                       // constant after unroll
        if (rr + 1 < RT) {
            if (((rr + 1) & 1) == 0) xa_ = col4[(rr + 1) * 64];
            else                     xb_ = col4[(rr + 1) * 64];
        }
        ROUND_BODY(rr, rr, (rr >= RC))
        if (rr + 1 < RT)
            WSTORE(((Q0 - rr - 1) % 6 + 6) % 6, col4[(Q0 - rr - 1) * 64]);
    }

    // ---- finalize: x2 + center term for even lags, local argmax ----
    #pragma unroll
    for (int j = 0; j < J; ++j) {
        float v2 = acc[j] + acc[j];
        if ((N0 + j) % 2 == 0) {
            const int R = (N0 + j) / 2;              // constant after unroll
            const float c = colf[(R / 4) * 256 + (R & 3)];
            v2 = fmaf(c, c, v2);
        }
        if (v2 > best) { best = v2; bl = N0 + j; }   // strict >: first max
    }
#undef ROUND_BODY
#undef WSTORE
#undef WREAD
}

__global__ __launch_bounds__(256)
void pitch_kernel(const float* __restrict__ audio, float* __restrict__ out) {
    __shared__ float4 X4[40 * 64];                   // 40960 B exactly
    float* Xa = reinterpret_cast<float*>(X4);

    const int tid = threadIdx.x;
    const int s   = tid >> 6;          // wave id
    const int f   = tid & 63;          // frame within block
    const int blk = blockIdx.x;
    const int b   = blk >> 6;          // batch row
    const int t0  = (blk & 63) << 6;   // first frame of block

    #pragma unroll 1
    for (int rep = 0; rep < 2; ++rep) {
        // opaque zero: defeats CSE/LICM of the rep-2 global loads without
        // changing addresses (keeps v[] live range inside the loop)
        int zoff;
        asm volatile("s_mov_b32 %0, 0" : "=s"(zoff));

        // ---- Phase A: load 40 samples of frame f (chunk s), partial sum ----
        const float* g = audio + (size_t)b * SAMPLES
                       + (size_t)(t0 + f) * HOPSZ + s * 40 + zoff;
        float v[40];
        float ps = 0.f;
        #pragma unroll
        for (int j = 0; j < 10; ++j) {
            float4 q = reinterpret_cast<const float4*>(g)[j];   // 16B-aligned
            v[4*j+0] = q.x; v[4*j+1] = q.y; v[4*j+2] = q.z; v[4*j+3] = q.w;
            ps += q.x + q.y + q.z + q.w;
        }

        // ---- Phase B: block mean via aux rows; pm stays in a register ----
        __syncthreads();                   // protect aux from prev rep's F
        Xa[s * 64 + f] = ps;
        __syncthreads();
        const float mu = (Xa[f] + Xa[64 + f] + Xa[128 + f] + Xa[192 + f])
                         * (1.0f / 160.0f);
        float pm = 0.f;
        #pragma unroll
        for (int q = 0; q < 40; ++q) pm = fmaxf(pm, fabsf(v[q] - mu));
        __syncthreads();                   // sum-reads done before D overwrites

        // ---- Phase D: write centered frames as row-quads ----
        #pragma unroll
        for (int k = 0; k < 10; ++k)
            X4[(10 * s + k) * 64 + f] =
                make_float4(v[4*k+0] - mu, v[4*k+1] - mu,
                            v[4*k+2] - mu, v[4*k+3] - mu);
        __syncthreads();

        // ---- Phase E: paired balanced tiles (rounds 27/27/28/28) ----
        const float4* col4 = X4 + f;
        const float*  colf = Xa + 4 * f;
        float best = -3.4e38f; int bl = 0;
        if      (s == 0) { conv_tile< 40>(col4, colf, best, bl);
                           conv_tile<145>(col4, colf, best, bl); }
        else if (s == 1) { conv_tile< 55>(col4, colf, best, bl);
                           conv_tile<130>(col4, colf, best, bl); }
        else if (s == 2) { conv_tile< 70>(col4, colf, best, bl);
                           conv_tile<115>(col4, colf, best, bl); }
        else             { conv_tile< 85>(col4, colf, best, bl);
                           conv_tile<100>(col4, colf, best, bl); }
        __syncthreads();                   // conv done: X now dead

        // ---- Phase F: cross-wave argmax + silent-check via aux rows ----
        Xa[s * 64 + f] = best;
        reinterpret_cast<int*>(Xa)[256 + s * 64 + f] = bl;
        Xa[512 + s * 64 + f] = pm;
        __syncthreads();

        if (s == 0) {
            float bv = Xa[f];
            int   L  = reinterpret_cast<int*>(Xa)[256 + f];
            #pragma unroll
            for (int c = 1; c < 4; ++c) {
                const float vv = Xa[c * 64 + f];
                const int   lv = reinterpret_cast<int*>(Xa)[256 + c * 64 + f];
                if (vv > bv || (vv == bv && lv < L)) { bv = vv; L = lv; }
            }
            const float mx = fmaxf(fmaxf(Xa[512 + f], Xa[512 + 64 + f]),
                                   fmaxf(Xa[512 + 128 + f], Xa[512 + 192 + f]));
            const float pitch = SR_F / (float)L;
            out[(size_t)b * TFRAMES + t0 + f] = (mx < 1e-8f) ? 0.0f : pitch;
        }
    }
}

extern "C" void kernel_launch(void* const* d_in, const int* in_sizes, int n_in,
                              void* d_out, int out_size, void* d_ws, size_t ws_size,
                              hipStream_t stream) {
    const float* audio = (const float*)d_in[0];
    float* out = (float*)d_out;
    pitch_kernel<<<dim3(1024), dim3(256), 0, stream>>>(audio, out);
}

// Round 14
// 105.126 us; speedup vs baseline: 1.1673x; 1.1673x over previous
//
#include <hip/hip_runtime.h>

// SimplePitchEstimator on MI355X (gfx950).
// ac = irfft(rfft(x,512)^2) == linear self-convolution; y = x - mean(x);
// half-sum c[n] = 2*sum_{2i<n} y[i]*y[n-i] + (n even ? y[n/2]^2 : 0).
//
// Round-14: 512-thread blocks / 8 waves / 8 lag-sets for 8 waves-per-SIMD.
// Evidence (r13 diagnostic): T = 26 us single-pass, VALUBusy 33%, no spill.
// Issue model: conv ~6-7 us; the other ~19 us is stall (VMEM line scatter,
// LDS latency, 5 barrier convoys) badly hidden at 4 waves/SIMD (40960-B LDS
// caps 4 blocks/CU; 4-wave blocks = 1 wave/SIMD each). This round keeps the
// grid, LDS image, and per-lag summation order IDENTICAL (absmax-0 math from
// r12) but splits lags 8 ways (J=7 low tiles paired with J=8 high tiles,
// rounds/wave 26/26/26/26/26/26/25/25) so 4 blocks x 8 waves = 32 waves/CU =
// 8/SIMD (hw max). Smaller tiles cut conv live regs to ~52 -> expect VGPR
// 64-72 (8 waves/SIMD needs <=64; 7/SIMD at <=72 still >> 4).
//
//  * rotation conv (r12-validated): 6 named float4 window vars, slot =
//    quad % 6 (compile-time), refill b128 directly into rotating target,
//    x-quad 2-var ping-pong, runtime x6 trips + static masked tail.
//  * LDS 160 rows x 64 frames x 4 B = 40960 B exactly; mu folded at write;
//    aux reductions multiplexed into X rows (sums/best/lag/pm).
//  * staging: thread (f, s) loads 20 samples (5 float4) of frame f chunk s.

#define SR_F    16000.0f
#define HOPSZ   256
#define TFRAMES 4096
#define SAMPLES 1048576

#define CMP(v_, c_) ((c_) == 0 ? (v_).x : (c_) == 1 ? (v_).y : \
                     (c_) == 2 ? (v_).z : (v_).w)

template<int N0, int J>
__device__ __forceinline__ void conv_tile(const float4* __restrict__ col4,
                                          const float* __restrict__ colf,
                                          float& best, int& bl) {
    constexpr int B0   = ((N0 - 3) / 4) * 4;   // aligned window base row
    constexpr int Q0   = B0 / 4;               // base quad at round 0
    constexpr int KOFF = N0 - B0;              // 3..6
    constexpr int W4   = (N0 + J - 1) / 4 - Q0 + 1;  // window quads (3..4)
    constexpr int IC   = (N0 + J) / 2;         // i-count for max lag
    constexpr int RT   = (IC + 3) / 4;         // total rounds
    constexpr int RC   = (N0 + 1) / 8;         // clean rounds (8r+6 < N0)
    constexpr int T    = RC / 6;               // runtime x6 trips
    constexpr int R6   = 6 * T;                // first static round
    static_assert(KOFF >= 3 && KOFF <= 6, "KOFF range");
    static_assert(W4 >= 3 && W4 <= 5, "window quads");
    static_assert(KOFF + J - 1 <= 4 * W4 - 1, "w index bound");
    static_assert(RC >= 1 && RC <= RT - 1, "clean/ragged split");
    static_assert(Q0 - RT + 1 >= 0, "refill quad in range");

    float acc[J];
    #pragma unroll
    for (int j = 0; j < J; ++j) acc[j] = 0.f;

    float4 W0_, W1_, W2_, W3_, W4_, W5_, xa_, xb_;

#define WREAD(vi_, c_) \
    ((vi_) == 0 ? CMP(W0_, c_) : (vi_) == 1 ? CMP(W1_, c_) : \
     (vi_) == 2 ? CMP(W2_, c_) : (vi_) == 3 ? CMP(W3_, c_) : \
     (vi_) == 4 ? CMP(W4_, c_) : CMP(W5_, c_))

#define WSTORE(vi_, e_) do {                                              \
    if      ((vi_) == 0) W0_ = (e_); else if ((vi_) == 1) W1_ = (e_);     \
    else if ((vi_) == 2) W2_ = (e_); else if ((vi_) == 3) W3_ = (e_);     \
    else if ((vi_) == 4) W4_ = (e_); else                 W5_ = (e_);     \
    } while (0)

    // round with round-index R_ (mask/parity), rotation phase K_ = R_ mod 6
#define ROUND_BODY(K_, R_, MASKED_)                                       \
    {                                                                     \
        const float4 xc = ((R_) & 1) ? xb_ : xa_;                         \
        _Pragma("unroll")                                                 \
        for (int d = 0; d < 4; ++d) {                                     \
            const float xv = CMP(xc, d);                                  \
            _Pragma("unroll")                                             \
            for (int j = 0; j < J; ++j) {                                 \
                if (!(MASKED_) || (8 * (R_) + 2 * d < N0 + j)) {          \
                    const int g  = KOFF + j - d;                          \
                    const int vi = ((Q0 + g / 4 - (K_)) % 6 + 6) % 6;     \
                    acc[j] = fmaf(xv, WREAD(vi, g & 3), acc[j]);          \
                }                                                         \
            }                                                             \
        }                                                                 \
    }

    // init: window quads Q0..Q0+W4-1 into vars (quad % 6); zero spares
    #pragma unroll
    for (int i = 0; i < 6; ++i) {
        if (i < W4) WSTORE((Q0 + i) % 6, col4[(Q0 + i) * 64]);
        else        WSTORE((Q0 + i) % 6, make_float4(0.f, 0.f, 0.f, 0.f));
    }
    xa_ = col4[0];

    // runtime x6 trips: rounds r = 6t+k, all clean (prefetch r+1 valid)
    const float4* xq = col4;                 // x base: quad 6t
    const float4* wq = col4 + Q0 * 64;       // refill base: quad Q0-6t
    #pragma unroll 1
    for (int t = 0; t < T; ++t) {
        #pragma unroll
        for (int k = 0; k < 6; ++k) {
            if (((k + 1) & 1) == 0) xa_ = xq[(k + 1) * 64];
            else                    xb_ = xq[(k + 1) * 64];
            ROUND_BODY(k, k, 0)
            WSTORE(((Q0 - k - 1) % 6 + 6) % 6, wq[-(k + 1) * 64]);
        }
        xq += 6 * 64;
        wq -= 6 * 64;
    }

    // static rounds rr = R6..RT-1 (clean remainder + ragged)
    #pragma unroll
    for (int u = 0; u < RT - R6; ++u) {
        const int rr = R6 + u;                       // constant after unroll
        if (rr + 1 < RT) {
            if (((rr + 1) & 1) == 0) xa_ = col4[(rr + 1) * 64];
            else                     xb_ = col4[(rr + 1) * 64];
        }
        ROUND_BODY(rr, rr, (rr >= RC))
        if (rr + 1 < RT)
            WSTORE(((Q0 - rr - 1) % 6 + 6) % 6, col4[(Q0 - rr - 1) * 64]);
    }

    // finalize: x2 + center term for even lags, local argmax (first-max)
    #pragma unroll
    for (int j = 0; j < J; ++j) {
        float v2 = acc[j] + acc[j];
        if ((N0 + j) % 2 == 0) {
            const int R = (N0 + j) / 2;              // constant after unroll
            const float c = colf[(R / 4) * 256 + (R & 3)];
            v2 = fmaf(c, c, v2);
        }
        if (v2 > best) { best = v2; bl = N0 + j; }
    }
#undef ROUND_BODY
#undef WSTORE
#undef WREAD
}

__global__ __launch_bounds__(512)
void pitch_kernel(const float* __restrict__ audio, float* __restrict__ out) {
    __shared__ float4 X4[40 * 64];                   // 40960 B exactly
    float* Xa = reinterpret_cast<float*>(X4);

    const int tid = threadIdx.x;
    const int s   = tid >> 6;          // wave id 0..7
    const int f   = tid & 63;          // frame within block
    const int blk = blockIdx.x;
    const int b   = blk >> 6;          // batch row
    const int t0  = (blk & 63) << 6;   // first frame of block

    // ---- Phase A: load 20 samples of frame f (chunk s), partial sum ----
    const float* g = audio + (size_t)b * SAMPLES + (size_t)(t0 + f) * HOPSZ + s * 20;
    float v[20];
    float ps = 0.f;
    #pragma unroll
    for (int j = 0; j < 5; ++j) {
        float4 q = reinterpret_cast<const float4*>(g)[j];   // 16B-aligned
        v[4*j+0] = q.x; v[4*j+1] = q.y; v[4*j+2] = q.z; v[4*j+3] = q.w;
        ps += q.x + q.y + q.z + q.w;
    }

    // ---- Phase B: block mean via aux rows (8 partials); pm in register ----
    Xa[s * 64 + f] = ps;
    __syncthreads();
    float mu = 0.f;
    #pragma unroll
    for (int c = 0; c < 8; ++c) mu += Xa[c * 64 + f];
    mu *= (1.0f / 160.0f);
    float pm = 0.f;
    #pragma unroll
    for (int q = 0; q < 20; ++q) pm = fmaxf(pm, fabsf(v[q] - mu));
    __syncthreads();                       // sum-reads done before D overwrites

    // ---- Phase D: write centered frames as row-quads (b128, contiguous) ----
    #pragma unroll
    for (int k = 0; k < 5; ++k)
        X4[(5 * s + k) * 64 + f] =
            make_float4(v[4*k+0] - mu, v[4*k+1] - mu, v[4*k+2] - mu, v[4*k+3] - mu);
    __syncthreads();

    // ---- Phase E: 8 balanced tile pairs (rounds 26x6, 25x2) ----
    const float4* col4 = X4 + f;
    const float*  colf = Xa + 4 * f;
    float best = -3.4e38f; int bl = 0;
    if      (s == 0) { conv_tile<40, 7>(col4, colf, best, bl);
                       conv_tile<152, 8>(col4, colf, best, bl); }
    else if (s == 1) { conv_tile<47, 7>(col4, colf, best, bl);
                       conv_tile<144, 8>(col4, colf, best, bl); }
    else if (s == 2) { conv_tile<54, 7>(col4, colf, best, bl);
                       conv_tile<136, 8>(col4, colf, best, bl); }
    else if (s == 3) { conv_tile<61, 7>(col4, colf, best, bl);
                       conv_tile<128, 8>(col4, colf, best, bl); }
    else if (s == 4) { conv_tile<68, 7>(col4, colf, best, bl);
                       conv_tile<120, 8>(col4, colf, best, bl); }
    else if (s == 5) { conv_tile<75, 7>(col4, colf, best, bl);
                       conv_tile<112, 8>(col4, colf, best, bl); }
    else if (s == 6) { conv_tile<82, 7>(col4, colf, best, bl);
                       conv_tile<104, 8>(col4, colf, best, bl); }
    else             { conv_tile<89, 7>(col4, colf, best, bl);
                       conv_tile<96, 8>(col4, colf, best, bl); }
    __syncthreads();                       // conv done: X now dead

    // ---- Phase F: cross-wave argmax + silent-check via aux rows ----
    Xa[s * 64 + f] = best;
    reinterpret_cast<int*>(Xa)[512 + s * 64 + f] = bl;
    Xa[1024 + s * 64 + f] = pm;
    __syncthreads();

    if (s == 0) {
        float bv = Xa[f];
        int   L  = reinterpret_cast<int*>(Xa)[512 + f];
        float mx = Xa[1024 + f];
        #pragma unroll
        for (int c = 1; c < 8; ++c) {
            const float vv = Xa[c * 64 + f];
            const int   lv = reinterpret_cast<int*>(Xa)[512 + c * 64 + f];
            if (vv > bv || (vv == bv && lv < L)) { bv = vv; L = lv; }
            mx = fmaxf(mx, Xa[1024 + c * 64 + f]);
        }
        const float pitch = SR_F / (float)L;
        out[(size_t)b * TFRAMES + t0 + f] = (mx < 1e-8f) ? 0.0f : pitch;
    }
}

extern "C" void kernel_launch(void* const* d_in, const int* in_sizes, int n_in,
                              void* d_out, int out_size, void* d_ws, size_t ws_size,
                              hipStream_t stream) {
    const float* audio = (const float*)d_in[0];
    float* out = (float*)d_out;
    pitch_kernel<<<dim3(1024), dim3(512), 0, stream>>>(audio, out);
}

// Round 15
// 97.194 us; speedup vs baseline: 1.2626x; 1.0816x over previous
//
#include <hip/hip_runtime.h>

// SimplePitchEstimator on MI355X (gfx950).
// ac = irfft(rfft(x,512)^2) == linear self-convolution; y = x - mean(x);
// half-sum c[n] = 2*sum_{2i<n} y[i]*y[n-i] + (n even ? y[n/2]^2 : 0).
//
// Round-15: r12 (best: dur 96.7, T ~26 us, absmax 0) + VGPR-trim staging.
// Evidence (r13): VGPR_Count 132 -> floor(512/132) = 3 waves/SIMD -> only 3
// of the 4 LDS-permitted blocks/CU resident -> ragged cohorts + barriers
// convoyed at 3 waves/SIMD (VALUBusy 33%). The 132 peak is staging's v[40]
// live across the phase-B mean reduce. r14's 8-wave split regressed (105 us:
// per-round overhead doubled, VGPR target missed) - reverted.
//
// Change: retain only HALF the chunk in registers (v4[5] = 20 regs); park the
// other 5 quads RAW in their final LDS slots during phase A (quads 10s+5..9,
// disjoint from the aux region = quad 0). After mu, each thread reads back
// its OWN slots (thread-private -> no barrier), subtracts, updates pm,
// rewrites. ps order / y values / conv / reductions bitwise-identical to r12.
// Cost ~+5 b128 LDS reads/thread; gain: VGPR <= 128 -> 4 waves/SIMD ->
// all 1024 blocks co-resident in ONE cohort.
//
//  * rotation conv (r12-validated): 6 named float4 window vars, slot =
//    quad % 6 compile-time, refill b128 into rotating target, x 2-var
//    ping-pong, runtime x6 trips + static masked tail.
//  * LDS 160x64x4 = 40960 B exactly; balanced pairs 27/27/28/28 rounds;
//    mu folded at LDS write; aux multiplexed into X (quad 0 + post-conv).

#define SR_F    16000.0f
#define HOPSZ   256
#define TFRAMES 4096
#define SAMPLES 1048576

#define CMP(v_, c_) ((c_) == 0 ? (v_).x : (c_) == 1 ? (v_).y : \
                     (c_) == 2 ? (v_).z : (v_).w)

template<int N0>
__device__ __forceinline__ void conv_tile(const float4* __restrict__ col4,
                                          const float* __restrict__ colf,
                                          float& best, int& bl) {
    constexpr int J    = 15;
    constexpr int B0   = ((N0 - 3) / 4) * 4;   // aligned window base row
    constexpr int Q0   = B0 / 4;               // base quad at round 0
    constexpr int KOFF = N0 - B0;              // 3..6
    constexpr int IC   = (N0 + J) / 2;         // i-count for max lag
    constexpr int RT   = (IC + 3) / 4;         // total rounds
    constexpr int RC   = (N0 - 6 + 7) / 8;     // clean rounds (8r+6 < N0)
    constexpr int T    = RC / 6;               // runtime x6 trips
    constexpr int R6   = 6 * T;                // first static round
    static_assert(KOFF >= 3 && KOFF + J - 1 <= 20, "window index bound");
    static_assert(RC >= 1 && RC <= RT - 1, "clean/ragged split");
    static_assert(Q0 - RT + 1 >= 0, "refill quad in range");

    float acc[J];
    #pragma unroll
    for (int j = 0; j < J; ++j) acc[j] = 0.f;

    float4 W0_, W1_, W2_, W3_, W4_, W5_, xa_, xb_;

#define WREAD(vi_, c_) \
    ((vi_) == 0 ? CMP(W0_, c_) : (vi_) == 1 ? CMP(W1_, c_) : \
     (vi_) == 2 ? CMP(W2_, c_) : (vi_) == 3 ? CMP(W3_, c_) : \
     (vi_) == 4 ? CMP(W4_, c_) : CMP(W5_, c_))

#define WSTORE(vi_, e_) do {                                              \
    if      ((vi_) == 0) W0_ = (e_); else if ((vi_) == 1) W1_ = (e_);     \
    else if ((vi_) == 2) W2_ = (e_); else if ((vi_) == 3) W3_ = (e_);     \
    else if ((vi_) == 4) W4_ = (e_); else                 W5_ = (e_);     \
    } while (0)

#define ROUND_BODY(K_, R_, MASKED_)                                       \
    {                                                                     \
        const float4 xc = ((R_) & 1) ? xb_ : xa_;                         \
        _Pragma("unroll")                                                 \
        for (int d = 0; d < 4; ++d) {                                     \
            const float xv = CMP(xc, d);                                  \
            _Pragma("unroll")                                             \
            for (int j = 0; j < J; ++j) {                                 \
                if (!(MASKED_) || (8 * (R_) + 2 * d < N0 + j)) {          \
                    const int g  = KOFF + j - d;                          \
                    const int vi = ((Q0 + g / 4 - (K_)) % 6 + 6) % 6;     \
                    acc[j] = fmaf(xv, WREAD(vi, g & 3), acc[j]);          \
                }                                                         \
            }                                                             \
        }                                                                 \
    }

    // init: quads Q0..Q0+5 into vars (Q0+i)%6 (clip quads>39), x quad 0
    #pragma unroll
    for (int i = 0; i < 6; ++i) {
        const float4 q = (Q0 + i <= 39) ? col4[(Q0 + i) * 64]
                                        : make_float4(0.f, 0.f, 0.f, 0.f);
        WSTORE((Q0 + i) % 6, q);
    }
    xa_ = col4[0];

    // runtime x6 trips: rounds r = 6t+k, all clean
    const float4* xq = col4;                 // x base: quad 6t
    const float4* wq = col4 + Q0 * 64;       // refill base: quad Q0-6t
    #pragma unroll 1
    for (int t = 0; t < T; ++t) {
        #pragma unroll
        for (int k = 0; k < 6; ++k) {
            if (((k + 1) & 1) == 0) xa_ = xq[(k + 1) * 64];
            else                    xb_ = xq[(k + 1) * 64];
            ROUND_BODY(k, k, 0)
            WSTORE(((Q0 - k - 1) % 6 + 6) % 6, wq[-(k + 1) * 64]);
        }
        xq += 6 * 64;
        wq -= 6 * 64;
    }

    // static rounds rr = R6..RT-1 (clean remainder + ragged)
    #pragma unroll
    for (int u = 0; u < RT - R6; ++u) {
        const int rr = R6 + u;                       // constant after unroll
        if (rr + 1 < RT) {
            if (((rr + 1) & 1) == 0) xa_ = col4[(rr + 1) * 64];
            else                     xb_ = col4[(rr + 1) * 64];
        }
        ROUND_BODY(rr, rr, (rr >= RC))
        if (rr + 1 < RT)
            WSTORE(((Q0 - rr - 1) % 6 + 6) % 6, col4[(Q0 - rr - 1) * 64]);
    }

    // finalize: x2 + center term for even lags, local argmax (first-max)
    #pragma unroll
    for (int j = 0; j < J; ++j) {
        float v2 = acc[j] + acc[j];
        if ((N0 + j) % 2 == 0) {
            const int R = (N0 + j) / 2;              // constant after unroll
            const float c = colf[(R / 4) * 256 + (R & 3)];
            v2 = fmaf(c, c, v2);
        }
        if (v2 > best) { best = v2; bl = N0 + j; }
    }
#undef ROUND_BODY
#undef WSTORE
#undef WREAD
}

__global__ __launch_bounds__(256)
void pitch_kernel(const float* __restrict__ audio, float* __restrict__ out) {
    __shared__ float4 X4[40 * 64];                   // 40960 B exactly
    float* Xa = reinterpret_cast<float*>(X4);

    const int tid = threadIdx.x;
    const int s   = tid >> 6;          // wave id
    const int f   = tid & 63;          // frame within block
    const int blk = blockIdx.x;
    const int b   = blk >> 6;          // batch row
    const int t0  = (blk & 63) << 6;   // first frame of block

    // ---- Phase A: load 40 samples of frame f (chunk s); keep quads 0..4 in
    //      registers, park quads 5..9 RAW in their final LDS slots (these are
    //      quads 10s+5..10s+9, disjoint from the aux region = quad 0).
    const float4* g4 = reinterpret_cast<const float4*>(
        audio + (size_t)b * SAMPLES + (size_t)(t0 + f) * HOPSZ + s * 40);
    float4 v4[5];
    float ps = 0.f;
    #pragma unroll
    for (int j = 0; j < 5; ++j) {
        v4[j] = g4[j];
        ps += v4[j].x + v4[j].y + v4[j].z + v4[j].w;   // same order as r12
    }
    #pragma unroll
    for (int j = 5; j < 10; ++j) {
        const float4 q = g4[j];
        ps += q.x + q.y + q.z + q.w;
        X4[(10 * s + j) * 64 + f] = q;                 // raw park
    }

    // ---- Phase B: block mean via aux region (quad 0 = floats 0..255) ----
    Xa[s * 64 + f] = ps;
    __syncthreads();
    const float mu = (Xa[f] + Xa[64 + f] + Xa[128 + f] + Xa[192 + f]) * (1.0f / 160.0f);
    float pm = 0.f;
    #pragma unroll
    for (int k = 0; k < 5; ++k) {
        pm = fmaxf(pm, fabsf(v4[k].x - mu));
        pm = fmaxf(pm, fabsf(v4[k].y - mu));
        pm = fmaxf(pm, fabsf(v4[k].z - mu));
        pm = fmaxf(pm, fabsf(v4[k].w - mu));
    }
    __syncthreads();                       // aux reads done before D overwrites

    // ---- Phase D: write centered frames. Retained half from registers;
    //      parked half read back from OWN slots (no barrier needed), centered,
    //      pm-updated, rewritten in place.
    #pragma unroll
    for (int k = 0; k < 5; ++k)
        X4[(10 * s + k) * 64 + f] =
            make_float4(v4[k].x - mu, v4[k].y - mu, v4[k].z - mu, v4[k].w - mu);
    #pragma unroll
    for (int k = 5; k < 10; ++k) {
        const float4 q = X4[(10 * s + k) * 64 + f];    // own raw park
        const float4 y = make_float4(q.x - mu, q.y - mu, q.z - mu, q.w - mu);
        pm = fmaxf(pm, fmaxf(fmaxf(fabsf(y.x), fabsf(y.y)),
                             fmaxf(fabsf(y.z), fabsf(y.w))));
        X4[(10 * s + k) * 64 + f] = y;
    }
    __syncthreads();

    // ---- Phase E: paired balanced tiles (rounds 27/27/28/28) ----
    const float4* col4 = X4 + f;
    const float*  colf = Xa + 4 * f;
    float best = -3.4e38f; int bl = 0;
    if      (s == 0) { conv_tile< 40>(col4, colf, best, bl);
                       conv_tile<145>(col4, colf, best, bl); }
    else if (s == 1) { conv_tile< 55>(col4, colf, best, bl);
                       conv_tile<130>(col4, colf, best, bl); }
    else if (s == 2) { conv_tile< 70>(col4, colf, best, bl);
                       conv_tile<115>(col4, colf, best, bl); }
    else             { conv_tile< 85>(col4, colf, best, bl);
                       conv_tile<100>(col4, colf, best, bl); }
    __syncthreads();                       // conv done: X now dead

    // ---- Phase F: cross-wave argmax + silent-check via aux rows ----
    Xa[s * 64 + f] = best;
    reinterpret_cast<int*>(Xa)[256 + s * 64 + f] = bl;
    Xa[512 + s * 64 + f] = pm;
    __syncthreads();

    if (s == 0) {
        float bv = Xa[f];
        int   L  = reinterpret_cast<int*>(Xa)[256 + f];
        #pragma unroll
        for (int c = 1; c < 4; ++c) {
            const float vv = Xa[c * 64 + f];
            const int   lv = reinterpret_cast<int*>(Xa)[256 + c * 64 + f];
            if (vv > bv || (vv == bv && lv < L)) { bv = vv; L = lv; }
        }
        const float mx = fmaxf(fmaxf(Xa[512 + f], Xa[512 + 64 + f]),
                               fmaxf(Xa[512 + 128 + f], Xa[512 + 192 + f]));
        const float pitch = SR_F / (float)L;
        out[(size_t)b * TFRAMES + t0 + f] = (mx < 1e-8f) ? 0.0f : pitch;
    }
}

extern "C" void kernel_launch(void* const* d_in, const int* in_sizes, int n_in,
                              void* d_out, int out_size, void* d_ws, size_t ws_size,
                              hipStream_t stream) {
    const float* audio = (const float*)d_in[0];
    float* out = (float*)d_out;
    pitch_kernel<<<dim3(1024), dim3(256), 0, stream>>>(audio, out);
}